// Round 1
// baseline (612.516 us; speedup 1.0000x reference)
//
#include <hip/hip_runtime.h>
#include <stdint.h>

#define BATCH 16
#define CDIM 64
#define NDIM 65536
#define EPSV 1e-6f

typedef __attribute__((ext_vector_type(8))) short bf16x8;
typedef __attribute__((ext_vector_type(4))) short bf16x4;
typedef __attribute__((ext_vector_type(4))) float f32x4;

static __device__ __forceinline__ uint32_t f2bf(float f) {
    uint32_t u = __builtin_bit_cast(uint32_t, f);
    return (u + 0x7fffu + ((u >> 16) & 1u)) >> 16;   // RNE
}
static __device__ __forceinline__ float bf2f(uint32_t h) {
    uint32_t u = h << 16;
    return __builtin_bit_cast(float, u);
}
static __device__ __forceinline__ uint32_t pack2(float a, float b) {
    return f2bf(a) | (f2bf(b) << 16);
}

// ---------------- Kernel 1: Gram matrix + tvec ----------------
// grid 512 = 16 batches x 32 tiles; each block: 4 chunks of 512 positions.
// LDS tile [64][520] bf16 (pad +8 keeps b128 rows 16B-aligned, banks uniform).
#define T1 512
#define P1 520
#define CHUNKS 4

__global__ __launch_bounds__(256, 2)
void gram_kernel(const float* __restrict__ x, float* __restrict__ mat,
                 float* __restrict__ tvec) {
    __shared__ __align__(16) short ldsU[CDIM][P1];
    __shared__ float ldsG[T1];
    __shared__ float red[4][CDIM];

    const int tid = threadIdx.x;
    const int b = blockIdx.x >> 5;
    const int tileIdx = blockIdx.x & 31;
    const int w = tid >> 6;        // wave id 0..3
    const int lane = tid & 63;
    const int cq = lane >> 4;      // quad
    const int cr = lane & 15;

    f32x4 acc0 = {0.f, 0.f, 0.f, 0.f};
    f32x4 acc1 = acc0, acc2 = acc0, acc3 = acc0;
    float tpart = 0.f;

    const float* xbase = x + (size_t)b * CDIM * NDIM;

    for (int chunk = 0; chunk < CHUNKS; ++chunk) {
        const int n0 = tileIdx * (T1 * CHUNKS) + chunk * T1;
        const float* xb = xbase + n0 + 2 * tid;
        float ss0 = 0.f, ss1 = 0.f, cs0 = 0.f, cs1 = 0.f;
        // load phase: thread owns positions 2*tid, 2*tid+1 of this chunk
#pragma unroll 8
        for (int c = 0; c < CDIM; ++c) {
            float2 v = *(const float2*)(xb + (size_t)c * NDIM);
            ss0 += v.x * v.x; ss1 += v.y * v.y;
            cs0 += v.x;       cs1 += v.y;
            *(uint32_t*)&ldsU[c][2 * tid] = pack2(v.x, v.y);
        }
        const float inv0 = 1.f / (sqrtf(ss0) + EPSV);
        const float inv1 = 1.f / (sqrtf(ss1) + EPSV);
        const float sq0 = sqrtf(inv0);
        const float sq1 = sqrtf(inv1);
        ldsG[2 * tid]     = inv0 * sq0 * cs0;   // g = inv^1.5 * colsum
        ldsG[2 * tid + 1] = inv1 * sq1 * cs1;
        // rescale own columns in place: u = v * sqrt(inv_norm)  (own data, no barrier)
#pragma unroll 8
        for (int c = 0; c < CDIM; ++c) {
            uint32_t p = *(uint32_t*)&ldsU[c][2 * tid];
            float a  = bf2f(p & 0xffffu) * sq0;
            float bb = bf2f(p >> 16) * sq1;
            *(uint32_t*)&ldsU[c][2 * tid] = pack2(a, bb);
        }
        __syncthreads();
        // MFMA Gram: wave w computes rows [16w,16w+16) x all 64 cols, K=512
#pragma unroll 4
        for (int ks = 0; ks < 16; ++ks) {
            const int k0 = ks * 32 + cq * 8;
            bf16x8 afrag = *(const bf16x8*)&ldsU[w * 16 + cr][k0];
            bf16x8 b0 = *(const bf16x8*)&ldsU[cr][k0];
            bf16x8 b1 = *(const bf16x8*)&ldsU[16 + cr][k0];
            bf16x8 b2 = *(const bf16x8*)&ldsU[32 + cr][k0];
            bf16x8 b3 = *(const bf16x8*)&ldsU[48 + cr][k0];
            acc0 = __builtin_amdgcn_mfma_f32_16x16x32_bf16(afrag, b0, acc0, 0, 0, 0);
            acc1 = __builtin_amdgcn_mfma_f32_16x16x32_bf16(afrag, b1, acc1, 0, 0, 0);
            acc2 = __builtin_amdgcn_mfma_f32_16x16x32_bf16(afrag, b2, acc2, 0, 0, 0);
            ac3_:
            acc3 = __builtin_amdgcn_mfma_f32_16x16x32_bf16(afrag, b3, acc3, 0, 0, 0);
        }
        // tvec partial: row=lane (channel), slice=w (128 positions); b128 reads,
        // ldsG reads are wave-uniform broadcasts.
#pragma unroll 4
        for (int i = 0; i < 16; ++i) {
            const int nb = w * 128 + i * 8;
            bf16x8 uf = *(const bf16x8*)&ldsU[lane][nb];
#pragma unroll
            for (int j = 0; j < 8; ++j) {
                tpart += bf2f((uint32_t)(uint16_t)uf[j]) * ldsG[nb + j];
            }
        }
        __syncthreads();
    }
    // reduce + emit tvec
    red[w][lane] = tpart;
    __syncthreads();
    if (tid < CDIM) {
        float s = red[0][tid] + red[1][tid] + red[2][tid] + red[3][tid];
        atomicAdd(&tvec[b * CDIM + tid], s);
    }
    // emit matrix: C/D layout col=lane&15, row=quad*4+reg
    float* mb = mat + (size_t)b * CDIM * CDIM;
    const f32x4 accs[4] = {acc0, acc1, acc2, acc3};
#pragma unroll
    for (int mt = 0; mt < 4; ++mt) {
#pragma unroll
        for (int r = 0; r < 4; ++r) {
            const int row = w * 16 + cq * 4 + r;
            const int col = mt * 16 + cr;
            atomicAdd(&mb[row * CDIM + col], accs[mt][r]);
        }
    }
}

// ---------------- Kernel 2: matvec + epilogue ----------------
// grid 4096 = 16 batches x 256 tiles of 256 positions (block order reversed
// for L3 locality against kernel 1's streaming tail).
#define T2 256
#define P2 68    // [n][c] bf16 tile, pad 64->68 (2-way banks, 8B-aligned b64 frags)
#define PM 72    // matrix bf16 LDS pitch (rows 144B, 16B-aligned b128 frags)

__global__ __launch_bounds__(256, 3)
void out_kernel(const float* __restrict__ x, const float* __restrict__ mat,
                const float* __restrict__ tvec, const float* __restrict__ gamma,
                float* __restrict__ out) {
    __shared__ __align__(16) short ldsV[T2][P2];
    __shared__ __align__(16) short ldsM[CDIM][PM];
    __shared__ float ldsCS[T2];
    __shared__ float ldsIN[T2];
    __shared__ float ldsTL[CDIM];

    const int tid = threadIdx.x;
    const int bid = (int)(gridDim.x - 1 - blockIdx.x);
    const int b = bid >> 8;
    const int n0 = (bid & 255) * T2;
    const int w = tid >> 6;
    const int lane = tid & 63;
    const int cq = lane >> 4;
    const int cr = lane & 15;

    // stage matrix (bf16) + tailor
    const float* mb = mat + (size_t)b * CDIM * CDIM;
#pragma unroll
    for (int i = 0; i < 16; ++i) {
        const int idx = tid + i * 256;
        ldsM[idx >> 6][idx & 63] = (short)f2bf(mb[idx]);
    }
    if (tid < CDIM)
        ldsTL[tid] = 1.f / ((float)NDIM + tvec[b * CDIM + tid] + EPSV);

    // load x tile transposed [n][c]; thread owns position n0+tid; local stats
    const float* xb = x + (size_t)b * CDIM * NDIM + n0 + tid;
    float ss = 0.f, cs = 0.f;
#pragma unroll 8
    for (int cp = 0; cp < 32; ++cp) {
        float v0 = xb[(size_t)(2 * cp) * NDIM];
        float v1 = xb[(size_t)(2 * cp + 1) * NDIM];
        ss += v0 * v0 + v1 * v1;
        cs += v0 + v1;
        *(uint32_t*)&ldsV[tid][2 * cp] = pack2(v0, v1);
    }
    ldsIN[tid] = 1.f / (sqrtf(ss) + EPSV);
    ldsCS[tid] = cs;
    __syncthreads();

    // A-frags from matrix (constant per batch): A[c][k=m]
    bf16x8 afrag[4][2];
#pragma unroll
    for (int ct = 0; ct < 4; ++ct)
#pragma unroll
        for (int ks = 0; ks < 2; ++ks)
            afrag[ct][ks] = *(const bf16x8*)&ldsM[ct * 16 + cr][ks * 32 + cq * 8];

    f32x4 acc[4][4];
#pragma unroll
    for (int p = 0; p < 4; ++p)
#pragma unroll
        for (int ct = 0; ct < 4; ++ct)
            acc[p][ct] = (f32x4){0.f, 0.f, 0.f, 0.f};

    // D(64 x 256) = M(64x64) @ V(64x256); wave w handles pos-tiles 4w..4w+3
#pragma unroll
    for (int p = 0; p < 4; ++p) {
        const int n = (w * 4 + p) * 16 + cr;
#pragma unroll
        for (int ks = 0; ks < 2; ++ks) {
            const int k0 = ks * 32 + cq * 8;
            bf16x4 lo = *(const bf16x4*)&ldsV[n][k0];
            bf16x4 hi = *(const bf16x4*)&ldsV[n][k0 + 4];
            bf16x8 bfrag = __builtin_shufflevector(lo, hi, 0, 1, 2, 3, 4, 5, 6, 7);
#pragma unroll
            for (int ct = 0; ct < 4; ++ct)
                acc[p][ct] = __builtin_amdgcn_mfma_f32_16x16x32_bf16(
                    afrag[ct][ks], bfrag, acc[p][ct], 0, 0, 0);
        }
    }

    // epilogue: out = x + gamma * tailor[c] * (colsum[n] + inv[n] * y[c,n])
    const float g = gamma[0];
    const float* xr = x + (size_t)b * CDIM * NDIM + n0;
    float* ob = out + (size_t)b * CDIM * NDIM + n0;
#pragma unroll
    for (int p = 0; p < 4; ++p) {
        const int n = (w * 4 + p) * 16 + cr;
        const float csn = ldsCS[n];
        const float invn = ldsIN[n];
#pragma unroll
        for (int ct = 0; ct < 4; ++ct) {
            const int c0 = ct * 16 + cq * 4;
#pragma unroll
            for (int r = 0; r < 4; ++r) {
                const int c = c0 + r;
                const float xv = xr[(size_t)c * NDIM + n];  // L2-hot re-read, exact fp32
                ob[(size_t)c * NDIM + n] =
                    xv + g * ldsTL[c] * (csn + invn * acc[p][ct][r]);
            }
        }
    }
}

extern "C" void kernel_launch(void* const* d_in, const int* in_sizes, int n_in,
                              void* d_out, int out_size, void* d_ws, size_t ws_size,
                              hipStream_t stream) {
    const float* x = (const float*)d_in[0];
    const float* gamma = (const float*)d_in[1];
    float* out = (float*)d_out;
    float* mat = (float*)d_ws;                       // 16*64*64 f32
    float* tvec = mat + BATCH * CDIM * CDIM;         // 16*64 f32
    hipMemsetAsync(d_ws, 0,
                   (size_t)(BATCH * CDIM * CDIM + BATCH * CDIM) * sizeof(float),
                   stream);
    hipLaunchKernelGGL(gram_kernel, dim3(BATCH * 32), dim3(256), 0, stream,
                       x, mat, tvec);
    hipLaunchKernelGGL(out_kernel, dim3(BATCH * 256), dim3(256), 0, stream,
                       x, mat, tvec, gamma, out);
}

// Round 2
// 555.503 us; speedup vs baseline: 1.1026x; 1.1026x over previous
//
#include <hip/hip_runtime.h>
#include <stdint.h>

#define BATCH 16
#define CDIM 64
#define NDIM 65536
#define EPSV 1e-6f

typedef __attribute__((ext_vector_type(8))) short bf16x8;
typedef __attribute__((ext_vector_type(4))) short bf16x4;
typedef __attribute__((ext_vector_type(4))) float f32x4;

static __device__ __forceinline__ uint32_t f2bf(float f) {
    uint32_t u = __builtin_bit_cast(uint32_t, f);
    return (u + 0x7fffu + ((u >> 16) & 1u)) >> 16;   // RNE
}
static __device__ __forceinline__ float bf2f(uint32_t h) {
    uint32_t u = h << 16;
    return __builtin_bit_cast(float, u);
}

// ---------------- Kernel 1: Gram partials + tvec partials ----------------
// grid 1024 = 16 batches x 64 tiles; each block: 4 chunks of 256 positions.
// LDS ~36 KB -> 4 blocks/CU (16 waves) for latency hiding.
#define T1 256
#define P1 264   // bf16 row pitch; 528 B rows, 16B-aligned b128 frags
#define CHUNKS 4
#define NTILE1 64

__global__ __launch_bounds__(256, 4)
void gram_kernel(const float* __restrict__ x, float* __restrict__ pmat,
                 float* __restrict__ pt) {
    __shared__ __align__(16) short ldsU[CDIM][P1];
    __shared__ __align__(16) float ldsG[T1];
    __shared__ float red[4][CDIM];

    const int tid = threadIdx.x;
    const int b = blockIdx.x >> 6;
    const int tileIdx = blockIdx.x & 63;
    const int w = tid >> 6;
    const int lane = tid & 63;
    const int cq = lane >> 4;
    const int cr = lane & 15;

    f32x4 acc0 = {0.f, 0.f, 0.f, 0.f};
    f32x4 acc1 = acc0, acc2 = acc0, acc3 = acc0;
    float tpart = 0.f;

    const float* xbase = x + (size_t)b * CDIM * NDIM;

    for (int chunk = 0; chunk < CHUNKS; ++chunk) {
        const int n0 = tileIdx * (T1 * CHUNKS) + chunk * T1;
        const float* xb = xbase + n0 + tid;   // thread owns one position
        float ss = 0.f, cs = 0.f;
#pragma unroll 8
        for (int c = 0; c < CDIM; ++c) {
            float v = xb[(size_t)c * NDIM];
            ss += v * v;
            cs += v;
            ldsU[c][tid] = (short)f2bf(v);
        }
        const float inv = 1.f / (sqrtf(ss) + EPSV);
        const float sq = sqrtf(inv);
        ldsG[tid] = inv * sq * cs;            // g = inv^1.5 * colsum
        // rescale own column in place: u = v * sqrt(inv_norm)
#pragma unroll 8
        for (int c = 0; c < CDIM; ++c) {
            uint32_t h = (uint16_t)ldsU[c][tid];
            ldsU[c][tid] = (short)f2bf(bf2f(h) * sq);
        }
        __syncthreads();
        // MFMA Gram: wave w -> rows [16w,16w+16) x all 64 cols, K=256
#pragma unroll
        for (int ks = 0; ks < 8; ++ks) {
            const int k0 = ks * 32 + cq * 8;
            bf16x8 afrag = *(const bf16x8*)&ldsU[w * 16 + cr][k0];
            bf16x8 b0 = *(const bf16x8*)&ldsU[cr][k0];
            bf16x8 b1 = *(const bf16x8*)&ldsU[16 + cr][k0];
            bf16x8 b2 = *(const bf16x8*)&ldsU[32 + cr][k0];
            bf16x8 b3 = *(const bf16x8*)&ldsU[48 + cr][k0];
            acc0 = __builtin_amdgcn_mfma_f32_16x16x32_bf16(afrag, b0, acc0, 0, 0, 0);
            acc1 = __builtin_amdgcn_mfma_f32_16x16x32_bf16(afrag, b1, acc1, 0, 0, 0);
            acc2 = __builtin_amdgcn_mfma_f32_16x16x32_bf16(afrag, b2, acc2, 0, 0, 0);
            acc3 = __builtin_amdgcn_mfma_f32_16x16x32_bf16(afrag, b3, acc3, 0, 0, 0);
        }
        // tvec partial: row = lane (channel), wave slice = 64 positions
#pragma unroll
        for (int i = 0; i < 8; ++i) {
            const int nb = w * 64 + i * 8;
            bf16x8 uf = *(const bf16x8*)&ldsU[lane][nb];
            f32x4 g0 = *(const f32x4*)&ldsG[nb];
            f32x4 g1 = *(const f32x4*)&ldsG[nb + 4];
#pragma unroll
            for (int j = 0; j < 4; ++j) {
                tpart += bf2f((uint32_t)(uint16_t)uf[j]) * g0[j];
                tpart += bf2f((uint32_t)(uint16_t)uf[j + 4]) * g1[j];
            }
        }
        __syncthreads();
    }
    // reduce tvec partial across waves, emit per-block partials (no atomics)
    red[w][lane] = tpart;
    __syncthreads();
    if (tid < CDIM) {
        pt[(size_t)blockIdx.x * CDIM + tid] =
            red[0][tid] + red[1][tid] + red[2][tid] + red[3][tid];
    }
    // emit Gram partial: C/D layout col=lane&15, row=quad*4+reg
    float* pm = pmat + (size_t)blockIdx.x * CDIM * CDIM;
    const f32x4 accs[4] = {acc0, acc1, acc2, acc3};
#pragma unroll
    for (int mt = 0; mt < 4; ++mt) {
#pragma unroll
        for (int r = 0; r < 4; ++r) {
            const int row = w * 16 + cq * 4 + r;
            const int col = mt * 16 + cr;
            pm[row * CDIM + col] = accs[mt][r];
        }
    }
}

// ---------------- Kernel 1.5: reduce partials -> mat, tailor ----------------
__global__ __launch_bounds__(256, 4)
void reduce_kernel(const float* __restrict__ pmat, const float* __restrict__ pt,
                   float* __restrict__ mat, float* __restrict__ tl) {
    const int blk = blockIdx.x;
    const int tid = threadIdx.x;
    if (blk < 256) {            // mat: 16 batches x 4096 elems
        const int b = blk >> 4;
        const int o = (blk & 15) * 256 + tid;
        float s = 0.f;
#pragma unroll 8
        for (int t = 0; t < NTILE1; ++t)
            s += pmat[((size_t)(b * NTILE1 + t)) * (CDIM * CDIM) + o];
        mat[b * CDIM * CDIM + o] = s;
    } else {                    // tailor: 16 x 64
        const int idx = (blk - 256) * 256 + tid;
        const int b = idx >> 6;
        const int c = idx & 63;
        float s = 0.f;
#pragma unroll 8
        for (int t = 0; t < NTILE1; ++t)
            s += pt[(size_t)(b * NTILE1 + t) * CDIM + c];
        tl[idx] = 1.f / ((float)NDIM + s + EPSV);
    }
}

// ---------------- Kernel 2: matvec + fused epilogue ----------------
// grid 4096, reversed order for L3 locality vs kernel 1's streaming tail.
// Residual x comes from LDS (bf16) — no global x re-read.
#define T2 256
#define P2 68    // [n][c] bf16 tile: 8B-aligned b64 frags
#define PM 72    // matrix bf16 pitch: 144B rows, 16B-aligned b128 frags

__global__ __launch_bounds__(256, 3)
void out_kernel(const float* __restrict__ x, const float* __restrict__ mat,
                const float* __restrict__ tl, const float* __restrict__ gamma,
                float* __restrict__ out) {
    __shared__ __align__(16) short ldsV[T2][P2];
    __shared__ __align__(16) short ldsM[CDIM][PM];
    __shared__ float ldsCS[T2];
    __shared__ float ldsIN[T2];
    __shared__ float ldsTL[CDIM];

    const int tid = threadIdx.x;
    const int bid = (int)(gridDim.x - 1 - blockIdx.x);
    const int b = bid >> 8;
    const int n0 = (bid & 255) * T2;
    const int w = tid >> 6;
    const int lane = tid & 63;
    const int cq = lane >> 4;
    const int cr = lane & 15;

    // stage matrix (bf16) + tailor
    const float* mb = mat + (size_t)b * CDIM * CDIM;
#pragma unroll
    for (int i = 0; i < 16; ++i) {
        const int idx = tid + i * 256;
        ldsM[idx >> 6][idx & 63] = (short)f2bf(mb[idx]);
    }
    if (tid < CDIM) ldsTL[tid] = tl[b * CDIM + tid];

    // load x tile transposed [n][c]; thread owns position n0+tid
    const float* xb = x + (size_t)b * CDIM * NDIM + n0 + tid;
    float ss = 0.f, cs = 0.f;
#pragma unroll 8
    for (int cp = 0; cp < 32; ++cp) {
        float v0 = xb[(size_t)(2 * cp) * NDIM];
        float v1 = xb[(size_t)(2 * cp + 1) * NDIM];
        ss += v0 * v0 + v1 * v1;
        cs += v0 + v1;
        *(uint32_t*)&ldsV[tid][2 * cp] = f2bf(v0) | (f2bf(v1) << 16);
    }
    ldsIN[tid] = 1.f / (sqrtf(ss) + EPSV);
    ldsCS[tid] = cs;
    __syncthreads();

    // A-frags from matrix: A[c][k=m]
    bf16x8 afrag[4][2];
#pragma unroll
    for (int ct = 0; ct < 4; ++ct)
#pragma unroll
        for (int ks = 0; ks < 2; ++ks)
            afrag[ct][ks] = *(const bf16x8*)&ldsM[ct * 16 + cr][ks * 32 + cq * 8];

    f32x4 acc[4][4];
#pragma unroll
    for (int p = 0; p < 4; ++p)
#pragma unroll
        for (int ct = 0; ct < 4; ++ct)
            acc[p][ct] = (f32x4){0.f, 0.f, 0.f, 0.f};

    // D(64 x 256) = M(64x64) @ V(64x256); wave w handles pos-tiles 4w..4w+3
#pragma unroll
    for (int p = 0; p < 4; ++p) {
        const int n = (w * 4 + p) * 16 + cr;
#pragma unroll
        for (int ks = 0; ks < 2; ++ks) {
            const int k0 = ks * 32 + cq * 8;
            bf16x4 lo = *(const bf16x4*)&ldsV[n][k0];
            bf16x4 hi = *(const bf16x4*)&ldsV[n][k0 + 4];
            bf16x8 bfrag = __builtin_shufflevector(lo, hi, 0, 1, 2, 3, 4, 5, 6, 7);
#pragma unroll
            for (int ct = 0; ct < 4; ++ct)
                acc[p][ct] = __builtin_amdgcn_mfma_f32_16x16x32_bf16(
                    afrag[ct][ks], bfrag, acc[p][ct], 0, 0, 0);
        }
    }

    // epilogue: out = x(bf16 from LDS) + gamma * tl[c] * (cs[n] + inv[n]*y[c,n])
    const float g = gamma[0];
    float* ob = out + (size_t)b * CDIM * NDIM + n0;
#pragma unroll
    for (int p = 0; p < 4; ++p) {
        const int n = (w * 4 + p) * 16 + cr;
        const float csn = ldsCS[n];
        const float invn = ldsIN[n];
#pragma unroll
        for (int ct = 0; ct < 4; ++ct) {
            const int c0 = ct * 16 + cq * 4;
            bf16x4 xv4 = *(const bf16x4*)&ldsV[n][c0];
#pragma unroll
            for (int r = 0; r < 4; ++r) {
                const int c = c0 + r;
                ob[(size_t)c * NDIM + n] =
                    bf2f((uint32_t)(uint16_t)xv4[r]) +
                    g * ldsTL[c] * (csn + invn * acc[p][ct][r]);
            }
        }
    }
}

extern "C" void kernel_launch(void* const* d_in, const int* in_sizes, int n_in,
                              void* d_out, int out_size, void* d_ws, size_t ws_size,
                              hipStream_t stream) {
    const float* x = (const float*)d_in[0];
    const float* gamma = (const float*)d_in[1];
    float* out = (float*)d_out;
    float* pmat = (float*)d_ws;                            // 1024 x 4096 f32
    float* pt = pmat + (size_t)1024 * CDIM * CDIM;         // 1024 x 64 f32
    float* mat = pt + (size_t)1024 * CDIM;                 // 16 x 4096 f32
    float* tl = mat + BATCH * CDIM * CDIM;                 // 16 x 64 f32
    hipLaunchKernelGGL(gram_kernel, dim3(BATCH * NTILE1), dim3(256), 0, stream,
                       x, pmat, pt);
    hipLaunchKernelGGL(reduce_kernel, dim3(260), dim3(256), 0, stream,
                       pmat, pt, mat, tl);
    hipLaunchKernelGGL(out_kernel, dim3(BATCH * 256), dim3(256), 0, stream,
                       x, mat, tl, gamma, out);
}